// Round 20
// baseline (193.779 us; speedup 1.0000x reference)
//
#include <hip/hip_runtime.h>
#include <cstdint>
#include <cmath>

#define HH 512
#define WW 512
#define NB 8
#define NC 11
#define NPIX (HH*WW)
#define NWPR 8                 // 512/64 words per row
#define NWORDS (HH*NWPR)       // 4096 u64 words per image-channel

typedef unsigned long long u64;
typedef uint32_t u32;
typedef unsigned short u16;

__device__ __forceinline__ int reflect512(int t) {
  t = t < 0 ? -t : t;
  return t > 511 ? 1022 - t : t;
}
__device__ __forceinline__ float h2f(u16 h) {
  _Float16 v = __builtin_bit_cast(_Float16, h);
  return (float)v;
}
__device__ __forceinline__ u16 f2h(float f) {
  _Float16 v = (_Float16)f;
  return __builtin_bit_cast(u16, v);
}

// ---------------- Stage 0: bit-packed onehot planes ----------------
__global__ __launch_bounds__(256) void k_onehot(const int* __restrict__ gt,
                                                u64* __restrict__ planes) {
  int wave = (blockIdx.x * 256 + threadIdx.x) >> 6;   // 0..4095
  int lane = threadIdx.x & 63;
  for (int j = wave; j < NB*512*8; j += 4096) {
    int img = j >> 12;
    int rw = j & 4095;
    int gv = gt[(size_t)img*NPIX + rw*64 + lane];
    u64 my = 0;
    #pragma unroll
    for (int c = 0; c < NC; ++c) {
      u64 m = __ballot(gv == c);
      if (lane == c) my = m;
    }
    if (lane < NC)
      planes[(size_t)img*NC*NWORDS + (size_t)lane*NWORDS + rw] = my;
  }
}

// ---------------- Stage A (fused): edges (VALU-bound) || pd-LSE (BW-bound) ----------------
#define TA 64

__global__ __launch_bounds__(256) void k_edges_lse(const u64* __restrict__ planes,
                                                   u64* __restrict__ strongw,
                                                   u64* __restrict__ weakw,
                                                   const float* __restrict__ pd,
                                                   const int* __restrict__ gt,
                                                   const float* __restrict__ wt,
                                                   float* __restrict__ tbuf,
                                                   double* __restrict__ acc) {
  __shared__ u64 sbits[72][2];       // 1152 B
  __shared__ u16 sbh[68*68];         // 9248 B  (blurred tile, fp16 bits)
  __shared__ u16 su[68*72];          // 9792 B  (t1 fp16, then mag^2-fp16|axis u16)
  __shared__ float red[4];
  __shared__ u16 slut[32];

  const int tid = threadIdx.x;
  const int bid = blockIdx.x;
  const int grpi = bid / 15;
  const int role = bid - grpi*15;

  if (role >= 11) {
    // ---- LSE role: term1 accumulate + tbuf write ----
    int j = grpi*4 + (role - 11);
    int t = j * 256 + tid;
    int b = t >> 16;                 // NPIX/4 = 65536 groups per image
    int p = (t & 65535) * 4;
    int4 g4 = *(const int4*)(gt + (size_t)b*NPIX + p);
    const float* pb = pd + (size_t)b * NC * NPIX + p;
    float s0=0.f,s1=0.f,s2=0.f,s3=0.f;
    float v0=0.f,v1=0.f,v2=0.f,v3=0.f;
    #pragma unroll
    for (int c = 0; c < NC; ++c) {
      float4 x = *(const float4*)(pb + (size_t)c * NPIX);
      if (c == g4.x) v0 = x.x;
      if (c == g4.y) v1 = x.y;
      if (c == g4.z) v2 = x.z;
      if (c == g4.w) v3 = x.w;
      s0 += __expf(x.x);
      s1 += __expf(x.y);
      s2 += __expf(x.z);
      s3 += __expf(x.w);
    }
    float4 o;
    o.x = wt[g4.x] * (v0 - __logf(s0));
    o.y = wt[g4.y] * (v1 - __logf(s1));
    o.z = wt[g4.z] * (v2 - __logf(s2));
    o.w = wt[g4.w] * (v3 - __logf(s3));
    *(float4*)(tbuf + (size_t)b*NPIX + p) = o;
    float s = o.x + o.y + o.z + o.w;
    #pragma unroll
    for (int off = 32; off > 0; off >>= 1) s += __shfl_down(s, off, 64);
    if ((tid & 63) == 0) red[tid >> 6] = s;
    __syncthreads();
    if (tid == 0) {
      double d = (double)red[0] + (double)red[1] + (double)red[2] + (double)red[3];
      atomicAdd(acc, d);
    }
    return;
  }

  // ---- Edge role ----
  const int e = grpi*11 + role;        // 0..5631
  const int z = e >> 6;                // channel-image
  const int rem = e & 63;
  const int r0 = (rem >> 3) * TA, c0 = (rem & 7) * TA;
  const u64* plane = planes + (size_t)z * NWORDS;

  const float g0 = 0.054488684549642945f;
  const float g1 = 0.24420134200323332f;
  const float g2 = 0.4026199468942475f;

  // vblur LUT (fp16 bits): value of a pixel's 5-bit vertical column
  if (tid < 32) {
    float v = ((tid & 1) ? g0 : 0.f) + ((tid & 2) ? g1 : 0.f) + ((tid & 4) ? g2 : 0.f)
            + ((tid & 8) ? g1 : 0.f) + ((tid & 16) ? g0 : 0.f);
    slut[tid] = f2h(v);
  }

  if (tid < 72) {
    int gr = reflect512(r0 + tid - 4);
    const u64* prow = plane + gr*8;
    int wi = c0 >> 6;
    u64 b = prow[wi];
    u64 w0, w1;
    if (c0 == 0) {
      u64 cc = prow[1];
      w0 = (b << 4) | ((__brevll(b) >> 59) & 0xFull);
      w1 = (b >> 60) | (cc << 4);
    } else if (c0 == WW - TA) {
      u64 a = prow[wi-1];
      w0 = (a >> 60) | (b << 4);
      w1 = (b >> 60) | (((__brevll(b) >> 1) & 0xFull) << 4);
    } else {
      u64 a = prow[wi-1];
      u64 cc = prow[wi+1];
      w0 = (a >> 60) | (b << 4);
      w1 = (b >> 60) | (cc << 4);
    }
    sbits[tid][0] = w0;
    sbits[tid][1] = w1;
  }
  __syncthreads();

  // --- vertical blur via 32-entry fp16 LUT (no cvt) ---
  u16* t1h = su;
  {
    int grp = tid % 18, row = tid / 18;
    for (int k = 0; k < 5; ++k) {
      if (row < 68) {
        int widx = grp >> 4;
        int shift = (grp & 15) * 4;
        u32 idx4 = 0;
        #pragma unroll
        for (int d = 0; d < 5; ++d) {
          u32 nib = (u32)(sbits[row+d][widx] >> shift) & 0xFu;
          u32 sp = (nib * 0x00204081u) & 0x01010101u;
          idx4 |= sp << d;
        }
        ushort4 o;
        o.x = slut[idx4 & 31u];
        o.y = slut[(idx4 >> 8) & 31u];
        o.z = slut[(idx4 >> 16) & 31u];
        o.w = slut[idx4 >> 24];
        *(ushort4*)&t1h[row*72 + grp*4] = o;
      }
      grp += 4; row += 14;
      if (grp >= 18) { grp -= 18; row += 1; }
    }
  }
  __syncthreads();

  // --- horizontal blur: fp16 in, f32 math, fp16 out ---
  {
    int grp = tid % 17, row = tid / 17;
    for (int k = 0; k < 5; ++k) {
      if (row < 68) {
        const u16* rp = &t1h[row*72 + grp*4];
        ushort4 ua = *(const ushort4*)rp;
        ushort4 ub = *(const ushort4*)(rp + 4);
        float a0=h2f(ua.x), a1=h2f(ua.y), a2=h2f(ua.z), a3=h2f(ua.w);
        float b0=h2f(ub.x), b1=h2f(ub.y), b2=h2f(ub.z), b3=h2f(ub.w);
        ushort4 o;
        o.x = f2h(g0*(a0 + b0) + g1*(a1 + a3) + g2*a2);
        o.y = f2h(g0*(a1 + b1) + g1*(a2 + b0) + g2*a3);
        o.z = f2h(g0*(a2 + b2) + g1*(a3 + b1) + g2*b0);
        o.w = f2h(g0*(a3 + b3) + g1*(b0 + b2) + g2*b1);
        *(ushort4*)&sbh[row*68 + grp*4] = o;
      }
      grp += 1; row += 15;
      if (grp >= 17) { grp -= 17; row += 1; }
    }
  }
  __syncthreads();

  // --- bake Sobel edge-clamp into sbh (border blocks only) ---
  {
    const bool rb0 = (r0 == 0), rb1 = (r0 == HH-TA);
    const bool cb0 = (c0 == 0), cb1 = (c0 == WW-TA);
    if (rb0 | rb1 | cb0 | cb1) {
      for (int i = tid; i < 528; i += 256) {
        int rr, cc;
        if (i < 272) {
          int rI = i / 68;
          rr = (rI < 2) ? rI : 64 + rI;
          cc = i - rI*68;
        } else {
          int j = i - 272;
          rr = 2 + (j >> 2);
          int cI = j & 3;
          cc = (cI < 2) ? cI : 64 + cI;
        }
        int sr = (rb0 && rr < 2) ? 2 : ((rb1 && rr > 65) ? 65 : rr);
        int sc = (cb0 && cc < 2) ? 2 : ((cb1 && cc > 65) ? 65 : cc);
        if (sr != rr || sc != cc) sbh[rr*68 + cc] = sbh[sr*68 + sc];
      }
      __syncthreads();
    }
  }

  // --- sobel -> mag^2 as fp16-bits|axis (u16); ordered-int NMS later ---
  u16* mgh = su;   // t1 dead
  for (int k = 0; k < 5; ++k) {
    int idx = tid + 256*k;
    if (idx < 66*16) {
      int row = idx >> 4;
      int g = idx & 15;
      int cbase = g*4;
      const u16* p0 = &sbh[row*68 + cbase];
      ushort4 a0 = *(const ushort4*)(p0);
      ushort2 b0 = *(const ushort2*)(p0 + 4);
      ushort4 a1 = *(const ushort4*)(p0 + 68);
      ushort2 b1 = *(const ushort2*)(p0 + 72);
      ushort4 a2 = *(const ushort4*)(p0 + 136);
      ushort2 b2 = *(const ushort2*)(p0 + 140);
      float ur[6], vr[6];
      {
        float t0, t1v, t2;
        t0 = h2f(a0.x); t1v = h2f(a1.x); t2 = h2f(a2.x);
        ur[0] = t0 + 2.f*t1v + t2;  vr[0] = t2 - t0;
        t0 = h2f(a0.y); t1v = h2f(a1.y); t2 = h2f(a2.y);
        ur[1] = t0 + 2.f*t1v + t2;  vr[1] = t2 - t0;
        t0 = h2f(a0.z); t1v = h2f(a1.z); t2 = h2f(a2.z);
        ur[2] = t0 + 2.f*t1v + t2;  vr[2] = t2 - t0;
        t0 = h2f(a0.w); t1v = h2f(a1.w); t2 = h2f(a2.w);
        ur[3] = t0 + 2.f*t1v + t2;  vr[3] = t2 - t0;
        t0 = h2f(b0.x); t1v = h2f(b1.x); t2 = h2f(b2.x);
        ur[4] = t0 + 2.f*t1v + t2;  vr[4] = t2 - t0;
        t0 = h2f(b0.y); t1v = h2f(b1.y); t2 = h2f(b2.y);
        ur[5] = t0 + 2.f*t1v + t2;  vr[5] = t2 - t0;
      }
      int gm = r0 + row - 1;
      ushort4 ov;
      u16* ovp = &ov.x;
      #pragma unroll
      for (int jj = 0; jj < 4; ++jj) {
        float gx = ur[jj+2] - ur[jj];
        float gy = vr[jj] + 2.f*vr[jj+1] + vr[jj+2];
        float gx2 = gx*gx, gy2 = gy*gy;
        float mvf = gx2 + gy2;
        int axis;
        if (gy2 <= 0.17157287525f*gx2) axis = 0;
        else if (gy2 >= 5.82842712475f*gx2) axis = 2;
        else axis = (gx*gy > 0.f) ? 1 : 3;
        int gmc = c0 + cbase + jj - 1;
        u16 bits = (u16)((f2h(mvf) & 0xFFFCu) | (u16)axis);
        bool in = ((unsigned)gm < 512u) && ((unsigned)gmc < 512u);
        ovp[jj] = in ? bits : (u16)0;
      }
      *(ushort4*)&mgh[row*68 + cbase] = ov;
    }
  }
  if (tid < 132) {
    int row = tid >> 1, col = 64 + (tid & 1);
    const u16* p0 = &sbh[row*68 + col];
    float b00=h2f(p0[0]),   b01=h2f(p0[1]),   b02=h2f(p0[2]);
    float b10=h2f(p0[68]),                     b12=h2f(p0[70]);
    float b20=h2f(p0[136]), b21=h2f(p0[137]), b22=h2f(p0[138]);
    float gx = (b02 + 2.f*b12 + b22) - (b00 + 2.f*b10 + b20);
    float gy = (b20 + 2.f*b21 + b22) - (b00 + 2.f*b01 + b02);
    float gx2 = gx*gx, gy2 = gy*gy;
    float mvf = gx2 + gy2;
    int axis;
    if (gy2 <= 0.17157287525f*gx2) axis = 0;
    else if (gy2 >= 5.82842712475f*gx2) axis = 2;
    else axis = (gx*gy > 0.f) ? 1 : 3;
    int gm = r0 + row - 1, gmc = c0 + col - 1;
    u16 bits = (u16)((f2h(mvf) & 0xFFFCu) | (u16)axis);
    bool in = ((unsigned)gm < 512u) && ((unsigned)gmc < 512u);
    mgh[row*68 + col] = in ? bits : (u16)0;
  }
  __syncthreads();

  // --- NMS + double threshold (u16 ordered-int compares) -> ballot words ---
  const int lane = tid & 63;
  const int wv = tid >> 6;
  const u32 THS = (u32)(f2h(0.039999f) & 0xFFFCu);   // 0.2^2 - eps, fp16-bit order
  const u32 THW = (u32)(f2h(0.009999f) & 0xFFFCu);   // 0.1^2 - eps
  size_t obase = (size_t)z * NWORDS + (size_t)r0*NWPR + (size_t)(c0 >> 6);
  for (int k = 0; k < 16; ++k) {
    int lr = wv + k*4;
    u32 mw = mgh[(lr+1)*68 + (lane+1)];
    u32 m = mw & 0xFFFCu;
    int a = mw & 3;
    int dr = ((0x01 >> (2*a)) & 3) - 1;
    int dc = ((0x1A >> (2*a)) & 3) - 1;
    u32 m1 = mgh[(lr+1+dr)*68 + (lane+1+dc)] & 0xFFFCu;
    u32 m2 = mgh[(lr+1-dr)*68 + (lane+1-dc)] & 0xFFFCu;
    bool pass = (m > m1) && (m > m2);
    u64 sw = __ballot(pass && m > THS);
    u64 wk = __ballot(pass && m > THW);
    if (lane == 0) {
      strongw[obase + (size_t)lr*NWPR] = sw;
      weakw  [obase + (size_t)lr*NWPR] = wk;
    }
  }
}

// ---------------- Stage B: hysteresis + dilate -> dc; last block per image does term2 ----------------
// (512,2): 1 workgroup/CU -> ~256 VGPR budget (R18's failure was the default 64-VGPR cap)
__global__ __launch_bounds__(512, 2) void k_hyst(const u64* __restrict__ strongw,
                                                 const u64* __restrict__ weakw,
                                                 const u64* __restrict__ planes,
                                                 u64* __restrict__ dc,
                                                 const float* __restrict__ tbuf,
                                                 double* __restrict__ acc,
                                                 double* __restrict__ acc2,
                                                 u32* __restrict__ cnt,
                                                 u32* __restrict__ hcnt,
                                                 float* __restrict__ out) {
  __shared__ u64 btop[8][8];
  __shared__ u64 bbot[8][8];
  __shared__ float fred[8];
  __shared__ int gflag;
  __shared__ int lastflag;
  const int z = blockIdx.x;
  const int tid = threadIdx.x;
  const int lane = tid & 63;
  const int w = tid >> 6;
  const int row = tid;
  const int img = z / NC;

  const u64* sg = strongw + (size_t)z * NWORDS + (size_t)row * NWPR;
  const u64* wg = weakw   + (size_t)z * NWORDS + (size_t)row * NWPR;

  u64 S[8], W[8], Wr[8];
  #pragma unroll
  for (int cw = 0; cw < 8; ++cw) { S[cw] = sg[cw]; W[cw] = wg[cw]; Wr[cw] = __brevll(W[cw]); }

  if (tid == 0) gflag = 0;
  if (lane == 0) {
    #pragma unroll
    for (int cw = 0; cw < 8; ++cw) btop[w][cw] = S[cw];
  }
  if (lane == 63) {
    #pragma unroll
    for (int cw = 0; cw < 8; ++cw) bbot[w][cw] = S[cw];
  }
  __syncthreads();

  for (int outer = 0; outer < 200; ++outer) {
    u64 up_b[8], dn_b[8];
    #pragma unroll
    for (int cw = 0; cw < 8; ++cw) {
      up_b[cw] = (w > 0) ? bbot[w-1][cw] : 0ull;
      dn_b[cw] = (w < 7) ? btop[w+1][cw] : 0ull;
    }
    int wchg = 0;
    for (int inner = 0; inner < 256; ++inner) {
      u64 v[8], changed = 0;
      #pragma unroll
      for (int cw = 0; cw < 8; ++cw) {
        u64 up = __shfl_up(S[cw], 1, 64);
        if (lane == 0) up = up_b[cw];
        u64 dn = __shfl_down(S[cw], 1, 64);
        if (lane == 63) dn = dn_b[cw];
        v[cw] = up | S[cw] | dn;
      }
      #pragma unroll
      for (int cw = 0; cw < 8; ++cw) {
        u64 vp = (cw > 0) ? v[cw-1] : 0ull;
        u64 vn = (cw < 7) ? v[cw+1] : 0ull;
        u64 D = (v[cw] << 1) | v[cw] | (v[cw] >> 1) | (vp >> 63) | (vn << 63);
        u64 seeds = W[cw] & D;
        u64 L = W[cw] & ~(W[cw] + seeds);
        u64 sr = __brevll(seeds);
        u64 R = __brevll(Wr[cw] & ~(Wr[cw] + sr));
        u64 ns = S[cw] | seeds | L | R;
        changed |= ns ^ S[cw];
        S[cw] = ns;
      }
      if (!__any(changed != 0ull)) break;
      wchg = 1;
    }
    if (wchg && lane == 0) gflag = 1;
    __syncthreads();
    if (lane == 0) {
      #pragma unroll
      for (int cw = 0; cw < 8; ++cw) btop[w][cw] = S[cw];
    }
    if (lane == 63) {
      #pragma unroll
      for (int cw = 0; cw < 8; ++cw) bbot[w][cw] = S[cw];
    }
    int f = gflag;
    __syncthreads();
    if (tid == 0) gflag = 0;
    __syncthreads();
    if (!f) break;
  }

  // in-register cross-dilate
  u64 d[8];
  #pragma unroll
  for (int cw = 0; cw < 8; ++cw) {
    u64 up = __shfl_up(S[cw], 1, 64);
    if (lane == 0) up = (w > 0) ? bbot[w-1][cw] : 0ull;
    u64 dn = __shfl_down(S[cw], 1, 64);
    if (lane == 63) dn = (w < 7) ? btop[w+1][cw] : 0ull;
    d[cw] = S[cw] | (S[cw] << 1) | (S[cw] >> 1) | up | dn;
  }
  #pragma unroll
  for (int cw = 0; cw < 8; ++cw) {
    if (cw > 0) d[cw] |= S[cw-1] >> 63;
    if (cw < 7) d[cw] |= S[cw+1] << 63;
  }

  // dc = dilated-edge AND own-class onehot (bits disjoint across channels)
  const u64* prow = planes + (size_t)z * NWORDS + (size_t)row * NWPR;
  u64* dgc = dc + (size_t)z * NWORDS + (size_t)row * NWPR;
  #pragma unroll
  for (int cw = 0; cw < 8; cw += 2) {
    ulonglong2 v2;
    v2.x = d[cw]   & prow[cw];
    v2.y = d[cw+1] & prow[cw+1];
    *(ulonglong2*)&dgc[cw] = v2;
  }

  // ---- last block of this image: dense term2 reduction ----
  __threadfence();
  __syncthreads();
  if (tid == 0) lastflag = (atomicAdd(&hcnt[img], 1u) == (u32)(NC - 1)) ? 1 : 0;
  __syncthreads();
  if (!lastflag) return;
  __threadfence();   // acquire: all 11 channel dc planes visible

  const u32* dc32 = (const u32*)dc;
  float s = 0.f;
  for (int k = 0; k < 16; ++k) {
    int wi = tid + (k << 9);                    // 0..8191
    u32 m = 0;
    #pragma unroll
    for (int c = 0; c < NC; ++c)
      m |= dc32[((size_t)(img*NC + c) << 13) + wi];
    const float* tb = tbuf + ((size_t)img << 18) + ((size_t)wi << 5);
    #pragma unroll
    for (int q = 0; q < 8; ++q) {
      float4 x = *(const float4*)(tb + q*4);
      if ((m >> (q*4))     & 1u) s += x.x;
      if ((m >> (q*4 + 1)) & 1u) s += x.y;
      if ((m >> (q*4 + 2)) & 1u) s += x.z;
      if ((m >> (q*4 + 3)) & 1u) s += x.w;
    }
  }
  #pragma unroll
  for (int o = 32; o > 0; o >>= 1) s += __shfl_down(s, o, 64);
  if (lane == 0) fred[w] = s;
  __syncthreads();
  if (tid == 0) {
    double dsum = 0.0;
    #pragma unroll
    for (int i = 0; i < 8; ++i) dsum += (double)fred[i];
    atomicAdd(acc2, dsum);
    __threadfence();
    u32 old = atomicAdd(cnt, 1u);
    if (old == (u32)(NB - 1)) {
      double t1 = atomicAdd(acc, 0.0);
      double t2 = atomicAdd(acc2, 0.0);
      out[0] = (float)(-(t1 + 2.0*t2) / 2097152.0);
    }
  }
}

extern "C" void kernel_launch(void* const* d_in, const int* in_sizes, int n_in,
                              void* d_out, int out_size, void* d_ws, size_t ws_size,
                              hipStream_t stream) {
  const float* pd = (const float*)d_in[0];
  const int*   gt = (const int*)d_in[1];
  const float* wt = (const float*)d_in[2];
  float* out = (float*)d_out;

  char* base = (char*)d_ws;
  double* acc  = (double*)base;
  double* acc2 = (double*)(base + 8);
  u32* cnt  = (u32*)(base + 16);
  u32* hcnt = (u32*)(base + 32);    // 8 u32
  u64* planes  = (u64*)(base + 256);
  u64* strongw = planes  + (size_t)NB*NC*NWORDS;
  u64* weakw   = strongw + (size_t)NB*NC*NWORDS;
  u64* dc      = weakw   + (size_t)NB*NC*NWORDS;
  float* tbuf  = (float*)(dc + (size_t)NB*NC*NWORDS);

  (void)hipMemsetAsync(d_ws, 0, 256, stream);

  k_onehot<<<1024, 256, 0, stream>>>(gt, planes);

  k_edges_lse<<<512*15, 256, 0, stream>>>(planes, strongw, weakw, pd, gt, wt, tbuf, acc);

  k_hyst<<<NB*NC, 512, 0, stream>>>(strongw, weakw, planes, dc, tbuf, acc, acc2, cnt, hcnt, out);
}

// Round 21
// 103.010 us; speedup vs baseline: 1.8812x; 1.8812x over previous
//
#include <hip/hip_runtime.h>
#include <cstdint>
#include <cmath>

#define HH 512
#define WW 512
#define NB 8
#define NC 11
#define NPIX (HH*WW)
#define NWPR 8                 // 512/64 words per row
#define NWORDS (HH*NWPR)       // 4096 u64 words per image-channel
#define NL2B 256               // k_loss2 blocks

typedef unsigned long long u64;
typedef uint32_t u32;
typedef unsigned short u16;

__device__ __forceinline__ int reflect512(int t) {
  t = t < 0 ? -t : t;
  return t > 511 ? 1022 - t : t;
}
__device__ __forceinline__ float h2f(u16 h) {
  _Float16 v = __builtin_bit_cast(_Float16, h);
  return (float)v;
}
__device__ __forceinline__ u16 f2h(float f) {
  _Float16 v = (_Float16)f;
  return __builtin_bit_cast(u16, v);
}

// ---------------- Stage 0: bit-packed onehot planes ----------------
__global__ __launch_bounds__(256) void k_onehot(const int* __restrict__ gt,
                                                u64* __restrict__ planes) {
  int wave = (blockIdx.x * 256 + threadIdx.x) >> 6;   // 0..4095
  int lane = threadIdx.x & 63;
  for (int j = wave; j < NB*512*8; j += 4096) {
    int img = j >> 12;
    int rw = j & 4095;
    int gv = gt[(size_t)img*NPIX + rw*64 + lane];
    u64 my = 0;
    #pragma unroll
    for (int c = 0; c < NC; ++c) {
      u64 m = __ballot(gv == c);
      if (lane == c) my = m;
    }
    if (lane < NC)
      planes[(size_t)img*NC*NWORDS + (size_t)lane*NWORDS + rw] = my;
  }
}

// ---------------- Stage A (fused): edges (VALU-bound) || pd-LSE (BW-bound) ----------------
#define TA 64

__global__ __launch_bounds__(256) void k_edges_lse(const u64* __restrict__ planes,
                                                   u64* __restrict__ strongw,
                                                   u64* __restrict__ weakw,
                                                   const float* __restrict__ pd,
                                                   const int* __restrict__ gt,
                                                   const float* __restrict__ wt,
                                                   float* __restrict__ tbuf,
                                                   double* __restrict__ acc) {
  __shared__ u64 sbits[72][2];       // 1152 B
  __shared__ u16 sbh[68*68];         // 9248 B  (blurred tile, fp16 bits)
  __shared__ u16 su[68*72];          // 9792 B  (t1 fp16, then mag^2-fp16|axis u16)
  __shared__ float red[4];
  __shared__ u16 slut[32];

  const int tid = threadIdx.x;
  const int bid = blockIdx.x;
  const int grpi = bid / 15;
  const int role = bid - grpi*15;

  if (role >= 11) {
    // ---- LSE role: term1 accumulate + tbuf write ----
    int j = grpi*4 + (role - 11);
    int t = j * 256 + tid;
    int b = t >> 16;                 // NPIX/4 = 65536 groups per image
    int p = (t & 65535) * 4;
    int4 g4 = *(const int4*)(gt + (size_t)b*NPIX + p);
    const float* pb = pd + (size_t)b * NC * NPIX + p;
    float s0=0.f,s1=0.f,s2=0.f,s3=0.f;
    float v0=0.f,v1=0.f,v2=0.f,v3=0.f;
    #pragma unroll
    for (int c = 0; c < NC; ++c) {
      float4 x = *(const float4*)(pb + (size_t)c * NPIX);
      if (c == g4.x) v0 = x.x;
      if (c == g4.y) v1 = x.y;
      if (c == g4.z) v2 = x.z;
      if (c == g4.w) v3 = x.w;
      s0 += __expf(x.x);
      s1 += __expf(x.y);
      s2 += __expf(x.z);
      s3 += __expf(x.w);
    }
    float4 o;
    o.x = wt[g4.x] * (v0 - __logf(s0));
    o.y = wt[g4.y] * (v1 - __logf(s1));
    o.z = wt[g4.z] * (v2 - __logf(s2));
    o.w = wt[g4.w] * (v3 - __logf(s3));
    *(float4*)(tbuf + (size_t)b*NPIX + p) = o;
    float s = o.x + o.y + o.z + o.w;
    #pragma unroll
    for (int off = 32; off > 0; off >>= 1) s += __shfl_down(s, off, 64);
    if ((tid & 63) == 0) red[tid >> 6] = s;
    __syncthreads();
    if (tid == 0) {
      double d = (double)red[0] + (double)red[1] + (double)red[2] + (double)red[3];
      atomicAdd(acc, d);
    }
    return;
  }

  // ---- Edge role ----
  const int e = grpi*11 + role;        // 0..5631
  const int z = e >> 6;                // channel-image
  const int rem = e & 63;
  const int r0 = (rem >> 3) * TA, c0 = (rem & 7) * TA;
  const u64* plane = planes + (size_t)z * NWORDS;

  const float g0 = 0.054488684549642945f;
  const float g1 = 0.24420134200323332f;
  const float g2 = 0.4026199468942475f;

  // vblur LUT (fp16 bits): value of a pixel's 5-bit vertical column
  if (tid < 32) {
    float v = ((tid & 1) ? g0 : 0.f) + ((tid & 2) ? g1 : 0.f) + ((tid & 4) ? g2 : 0.f)
            + ((tid & 8) ? g1 : 0.f) + ((tid & 16) ? g0 : 0.f);
    slut[tid] = f2h(v);
  }

  if (tid < 72) {
    int gr = reflect512(r0 + tid - 4);
    const u64* prow = plane + gr*8;
    int wi = c0 >> 6;
    u64 b = prow[wi];
    u64 w0, w1;
    if (c0 == 0) {
      u64 cc = prow[1];
      w0 = (b << 4) | ((__brevll(b) >> 59) & 0xFull);
      w1 = (b >> 60) | (cc << 4);
    } else if (c0 == WW - TA) {
      u64 a = prow[wi-1];
      w0 = (a >> 60) | (b << 4);
      w1 = (b >> 60) | (((__brevll(b) >> 1) & 0xFull) << 4);
    } else {
      u64 a = prow[wi-1];
      u64 cc = prow[wi+1];
      w0 = (a >> 60) | (b << 4);
      w1 = (b >> 60) | (cc << 4);
    }
    sbits[tid][0] = w0;
    sbits[tid][1] = w1;
  }
  __syncthreads();

  // --- vertical blur via 32-entry fp16 LUT (no cvt) ---
  u16* t1h = su;
  {
    int grp = tid % 18, row = tid / 18;
    for (int k = 0; k < 5; ++k) {
      if (row < 68) {
        int widx = grp >> 4;
        int shift = (grp & 15) * 4;
        u32 idx4 = 0;
        #pragma unroll
        for (int d = 0; d < 5; ++d) {
          u32 nib = (u32)(sbits[row+d][widx] >> shift) & 0xFu;
          u32 sp = (nib * 0x00204081u) & 0x01010101u;
          idx4 |= sp << d;
        }
        ushort4 o;
        o.x = slut[idx4 & 31u];
        o.y = slut[(idx4 >> 8) & 31u];
        o.z = slut[(idx4 >> 16) & 31u];
        o.w = slut[idx4 >> 24];
        *(ushort4*)&t1h[row*72 + grp*4] = o;
      }
      grp += 4; row += 14;
      if (grp >= 18) { grp -= 18; row += 1; }
    }
  }
  __syncthreads();

  // --- horizontal blur: fp16 in, f32 math, fp16 out ---
  {
    int grp = tid % 17, row = tid / 17;
    for (int k = 0; k < 5; ++k) {
      if (row < 68) {
        const u16* rp = &t1h[row*72 + grp*4];
        ushort4 ua = *(const ushort4*)rp;
        ushort4 ub = *(const ushort4*)(rp + 4);
        float a0=h2f(ua.x), a1=h2f(ua.y), a2=h2f(ua.z), a3=h2f(ua.w);
        float b0=h2f(ub.x), b1=h2f(ub.y), b2=h2f(ub.z), b3=h2f(ub.w);
        ushort4 o;
        o.x = f2h(g0*(a0 + b0) + g1*(a1 + a3) + g2*a2);
        o.y = f2h(g0*(a1 + b1) + g1*(a2 + b0) + g2*a3);
        o.z = f2h(g0*(a2 + b2) + g1*(a3 + b1) + g2*b0);
        o.w = f2h(g0*(a3 + b3) + g1*(b0 + b2) + g2*b1);
        *(ushort4*)&sbh[row*68 + grp*4] = o;
      }
      grp += 1; row += 15;
      if (grp >= 17) { grp -= 17; row += 1; }
    }
  }
  __syncthreads();

  // --- bake Sobel edge-clamp into sbh (border blocks only) ---
  {
    const bool rb0 = (r0 == 0), rb1 = (r0 == HH-TA);
    const bool cb0 = (c0 == 0), cb1 = (c0 == WW-TA);
    if (rb0 | rb1 | cb0 | cb1) {
      for (int i = tid; i < 528; i += 256) {
        int rr, cc;
        if (i < 272) {
          int rI = i / 68;
          rr = (rI < 2) ? rI : 64 + rI;
          cc = i - rI*68;
        } else {
          int j = i - 272;
          rr = 2 + (j >> 2);
          int cI = j & 3;
          cc = (cI < 2) ? cI : 64 + cI;
        }
        int sr = (rb0 && rr < 2) ? 2 : ((rb1 && rr > 65) ? 65 : rr);
        int sc = (cb0 && cc < 2) ? 2 : ((cb1 && cc > 65) ? 65 : cc);
        if (sr != rr || sc != cc) sbh[rr*68 + cc] = sbh[sr*68 + sc];
      }
      __syncthreads();
    }
  }

  // --- sobel -> mag^2 as fp16-bits|axis (u16); ordered-int NMS later ---
  u16* mgh = su;   // t1 dead
  for (int k = 0; k < 5; ++k) {
    int idx = tid + 256*k;
    if (idx < 66*16) {
      int row = idx >> 4;
      int g = idx & 15;
      int cbase = g*4;
      const u16* p0 = &sbh[row*68 + cbase];
      ushort4 a0 = *(const ushort4*)(p0);
      ushort2 b0 = *(const ushort2*)(p0 + 4);
      ushort4 a1 = *(const ushort4*)(p0 + 68);
      ushort2 b1 = *(const ushort2*)(p0 + 72);
      ushort4 a2 = *(const ushort4*)(p0 + 136);
      ushort2 b2 = *(const ushort2*)(p0 + 140);
      float ur[6], vr[6];
      {
        float t0, t1v, t2;
        t0 = h2f(a0.x); t1v = h2f(a1.x); t2 = h2f(a2.x);
        ur[0] = t0 + 2.f*t1v + t2;  vr[0] = t2 - t0;
        t0 = h2f(a0.y); t1v = h2f(a1.y); t2 = h2f(a2.y);
        ur[1] = t0 + 2.f*t1v + t2;  vr[1] = t2 - t0;
        t0 = h2f(a0.z); t1v = h2f(a1.z); t2 = h2f(a2.z);
        ur[2] = t0 + 2.f*t1v + t2;  vr[2] = t2 - t0;
        t0 = h2f(a0.w); t1v = h2f(a1.w); t2 = h2f(a2.w);
        ur[3] = t0 + 2.f*t1v + t2;  vr[3] = t2 - t0;
        t0 = h2f(b0.x); t1v = h2f(b1.x); t2 = h2f(b2.x);
        ur[4] = t0 + 2.f*t1v + t2;  vr[4] = t2 - t0;
        t0 = h2f(b0.y); t1v = h2f(b1.y); t2 = h2f(b2.y);
        ur[5] = t0 + 2.f*t1v + t2;  vr[5] = t2 - t0;
      }
      int gm = r0 + row - 1;
      ushort4 ov;
      u16* ovp = &ov.x;
      #pragma unroll
      for (int jj = 0; jj < 4; ++jj) {
        float gx = ur[jj+2] - ur[jj];
        float gy = vr[jj] + 2.f*vr[jj+1] + vr[jj+2];
        float gx2 = gx*gx, gy2 = gy*gy;
        float mvf = gx2 + gy2;
        int axis;
        if (gy2 <= 0.17157287525f*gx2) axis = 0;
        else if (gy2 >= 5.82842712475f*gx2) axis = 2;
        else axis = (gx*gy > 0.f) ? 1 : 3;
        int gmc = c0 + cbase + jj - 1;
        u16 bits = (u16)((f2h(mvf) & 0xFFFCu) | (u16)axis);
        bool in = ((unsigned)gm < 512u) && ((unsigned)gmc < 512u);
        ovp[jj] = in ? bits : (u16)0;
      }
      *(ushort4*)&mgh[row*68 + cbase] = ov;
    }
  }
  if (tid < 132) {
    int row = tid >> 1, col = 64 + (tid & 1);
    const u16* p0 = &sbh[row*68 + col];
    float b00=h2f(p0[0]),   b01=h2f(p0[1]),   b02=h2f(p0[2]);
    float b10=h2f(p0[68]),                     b12=h2f(p0[70]);
    float b20=h2f(p0[136]), b21=h2f(p0[137]), b22=h2f(p0[138]);
    float gx = (b02 + 2.f*b12 + b22) - (b00 + 2.f*b10 + b20);
    float gy = (b20 + 2.f*b21 + b22) - (b00 + 2.f*b01 + b02);
    float gx2 = gx*gx, gy2 = gy*gy;
    float mvf = gx2 + gy2;
    int axis;
    if (gy2 <= 0.17157287525f*gx2) axis = 0;
    else if (gy2 >= 5.82842712475f*gx2) axis = 2;
    else axis = (gx*gy > 0.f) ? 1 : 3;
    int gm = r0 + row - 1, gmc = c0 + col - 1;
    u16 bits = (u16)((f2h(mvf) & 0xFFFCu) | (u16)axis);
    bool in = ((unsigned)gm < 512u) && ((unsigned)gmc < 512u);
    mgh[row*68 + col] = in ? bits : (u16)0;
  }
  __syncthreads();

  // --- NMS + double threshold (u16 ordered-int compares) -> ballot words ---
  const int lane = tid & 63;
  const int wv = tid >> 6;
  const u32 THS = (u32)(f2h(0.039999f) & 0xFFFCu);   // 0.2^2 - eps, fp16-bit order
  const u32 THW = (u32)(f2h(0.009999f) & 0xFFFCu);   // 0.1^2 - eps
  size_t obase = (size_t)z * NWORDS + (size_t)r0*NWPR + (size_t)(c0 >> 6);
  for (int k = 0; k < 16; ++k) {
    int lr = wv + k*4;
    u32 mw = mgh[(lr+1)*68 + (lane+1)];
    u32 m = mw & 0xFFFCu;
    int a = mw & 3;
    int dr = ((0x01 >> (2*a)) & 3) - 1;
    int dc = ((0x1A >> (2*a)) & 3) - 1;
    u32 m1 = mgh[(lr+1+dr)*68 + (lane+1+dc)] & 0xFFFCu;
    u32 m2 = mgh[(lr+1-dr)*68 + (lane+1-dc)] & 0xFFFCu;
    bool pass = (m > m1) && (m > m2);
    u64 sw = __ballot(pass && m > THS);
    u64 wk = __ballot(pass && m > THW);
    if (lane == 0) {
      strongw[obase + (size_t)lr*NWPR] = sw;
      weakw  [obase + (size_t)lr*NWPR] = wk;
    }
  }
}

// ---------------- Stage B: hysteresis (carry-flood) + in-register dilate -> dc planes ----------------
__global__ __launch_bounds__(512, 2) void k_hyst(const u64* __restrict__ strongw,
                                                 const u64* __restrict__ weakw,
                                                 const u64* __restrict__ planes,
                                                 u64* __restrict__ dc) {
  __shared__ u64 btop[8][8];
  __shared__ u64 bbot[8][8];
  __shared__ int gflag;
  const int z = blockIdx.x;
  const int tid = threadIdx.x;
  const int lane = tid & 63;
  const int w = tid >> 6;
  const int row = tid;

  const u64* sg = strongw + (size_t)z * NWORDS + (size_t)row * NWPR;
  const u64* wg = weakw   + (size_t)z * NWORDS + (size_t)row * NWPR;

  u64 S[8], W[8], Wr[8];
  #pragma unroll
  for (int cw = 0; cw < 8; ++cw) { S[cw] = sg[cw]; W[cw] = wg[cw]; Wr[cw] = __brevll(W[cw]); }

  if (tid == 0) gflag = 0;
  if (lane == 0) {
    #pragma unroll
    for (int cw = 0; cw < 8; ++cw) btop[w][cw] = S[cw];
  }
  if (lane == 63) {
    #pragma unroll
    for (int cw = 0; cw < 8; ++cw) bbot[w][cw] = S[cw];
  }
  __syncthreads();

  for (int outer = 0; outer < 200; ++outer) {
    u64 up_b[8], dn_b[8];
    #pragma unroll
    for (int cw = 0; cw < 8; ++cw) {
      up_b[cw] = (w > 0) ? bbot[w-1][cw] : 0ull;
      dn_b[cw] = (w < 7) ? btop[w+1][cw] : 0ull;
    }
    int wchg = 0;
    for (int inner = 0; inner < 256; ++inner) {
      u64 v[8], changed = 0;
      #pragma unroll
      for (int cw = 0; cw < 8; ++cw) {
        u64 up = __shfl_up(S[cw], 1, 64);
        if (lane == 0) up = up_b[cw];
        u64 dn = __shfl_down(S[cw], 1, 64);
        if (lane == 63) dn = dn_b[cw];
        v[cw] = up | S[cw] | dn;
      }
      #pragma unroll
      for (int cw = 0; cw < 8; ++cw) {
        u64 vp = (cw > 0) ? v[cw-1] : 0ull;
        u64 vn = (cw < 7) ? v[cw+1] : 0ull;
        u64 D = (v[cw] << 1) | v[cw] | (v[cw] >> 1) | (vp >> 63) | (vn << 63);
        u64 seeds = W[cw] & D;
        u64 L = W[cw] & ~(W[cw] + seeds);
        u64 sr = __brevll(seeds);
        u64 R = __brevll(Wr[cw] & ~(Wr[cw] + sr));
        u64 ns = S[cw] | seeds | L | R;
        changed |= ns ^ S[cw];
        S[cw] = ns;
      }
      if (!__any(changed != 0ull)) break;
      wchg = 1;
    }
    if (wchg && lane == 0) gflag = 1;
    __syncthreads();
    if (lane == 0) {
      #pragma unroll
      for (int cw = 0; cw < 8; ++cw) btop[w][cw] = S[cw];
    }
    if (lane == 63) {
      #pragma unroll
      for (int cw = 0; cw < 8; ++cw) bbot[w][cw] = S[cw];
    }
    int f = gflag;
    __syncthreads();
    if (tid == 0) gflag = 0;
    __syncthreads();
    if (!f) break;
  }

  // in-register cross-dilate
  u64 d[8];
  #pragma unroll
  for (int cw = 0; cw < 8; ++cw) {
    u64 up = __shfl_up(S[cw], 1, 64);
    if (lane == 0) up = (w > 0) ? bbot[w-1][cw] : 0ull;
    u64 dn = __shfl_down(S[cw], 1, 64);
    if (lane == 63) dn = (w < 7) ? btop[w+1][cw] : 0ull;
    d[cw] = S[cw] | (S[cw] << 1) | (S[cw] >> 1) | up | dn;
  }
  #pragma unroll
  for (int cw = 0; cw < 8; ++cw) {
    if (cw > 0) d[cw] |= S[cw-1] >> 63;
    if (cw < 7) d[cw] |= S[cw+1] << 63;
  }

  // dc = dilated-edge AND own-class onehot (bits disjoint across channels)
  const u64* prow = planes + (size_t)z * NWORDS + (size_t)row * NWPR;
  u64* dgc = dc + (size_t)z * NWORDS + (size_t)row * NWPR;
  #pragma unroll
  for (int cw = 0; cw < 8; cw += 2) {
    ulonglong2 v2;
    v2.x = d[cw]   & prow[cw];
    v2.y = d[cw+1] & prow[cw+1];
    *(ulonglong2*)&dgc[cw] = v2;
  }
}

// ---------------- Stage C: dense OR-reduce term2 + final fold ----------------
__global__ __launch_bounds__(256) void k_loss2(const float* __restrict__ tbuf,
                                               const u32* __restrict__ dc32,
                                               double* __restrict__ acc,
                                               double* __restrict__ acc2,
                                               unsigned int* __restrict__ cnt,
                                               float* __restrict__ out) {
  int t = blockIdx.x * 256 + threadIdx.x;   // 65536 threads: one u32 word (32 px) each
  int img = t >> 13;                         // 8192 u32 words per image
  int wi = t & 8191;
  u32 m = 0;
  #pragma unroll
  for (int c = 0; c < NC; ++c)
    m |= dc32[((size_t)(img*NC + c) << 13) + wi];
  const float* tb = tbuf + ((size_t)img << 18) + ((size_t)wi << 5);
  float s = 0.f;
  #pragma unroll
  for (int q = 0; q < 8; ++q) {
    float4 x = *(const float4*)(tb + q*4);
    if ((m >> (q*4))     & 1u) s += x.x;
    if ((m >> (q*4 + 1)) & 1u) s += x.y;
    if ((m >> (q*4 + 2)) & 1u) s += x.z;
    if ((m >> (q*4 + 3)) & 1u) s += x.w;
  }
  #pragma unroll
  for (int o = 32; o > 0; o >>= 1) s += __shfl_down(s, o, 64);
  __shared__ float wsum[4];
  if ((threadIdx.x & 63) == 0) wsum[threadIdx.x >> 6] = s;
  __syncthreads();
  if (threadIdx.x == 0) {
    double d = (double)wsum[0] + (double)wsum[1] + (double)wsum[2] + (double)wsum[3];
    atomicAdd(acc2, d);
    __threadfence();
    unsigned int old = atomicAdd(cnt, 1u);
    if (old == NL2B - 1) {
      double t1 = atomicAdd(acc, 0.0);
      double t2 = atomicAdd(acc2, 0.0);
      out[0] = (float)(-(t1 + 2.0*t2) / 2097152.0);
    }
  }
}

extern "C" void kernel_launch(void* const* d_in, const int* in_sizes, int n_in,
                              void* d_out, int out_size, void* d_ws, size_t ws_size,
                              hipStream_t stream) {
  const float* pd = (const float*)d_in[0];
  const int*   gt = (const int*)d_in[1];
  const float* wt = (const float*)d_in[2];
  float* out = (float*)d_out;

  double* acc  = (double*)d_ws;
  double* acc2 = (double*)((char*)d_ws + 8);
  unsigned int* cnt = (unsigned int*)((char*)d_ws + 16);
  u64* planes  = (u64*)((char*)d_ws + 256);
  u64* strongw = planes  + (size_t)NB*NC*NWORDS;
  u64* weakw   = strongw + (size_t)NB*NC*NWORDS;
  u64* dc      = weakw   + (size_t)NB*NC*NWORDS;
  float* tbuf  = (float*)(dc + (size_t)NB*NC*NWORDS);

  (void)hipMemsetAsync(d_ws, 0, 256, stream);

  k_onehot<<<1024, 256, 0, stream>>>(gt, planes);

  k_edges_lse<<<512*15, 256, 0, stream>>>(planes, strongw, weakw, pd, gt, wt, tbuf, acc);

  k_hyst<<<NB*NC, 512, 0, stream>>>(strongw, weakw, planes, dc);

  k_loss2<<<NL2B, 256, 0, stream>>>(tbuf, (const u32*)dc, acc, acc2, cnt, out);
}